// Round 1
// baseline (4908.926 us; speedup 1.0000x reference)
//
#include <hip/hip_runtime.h>
#include <hip/hip_bf16.h>

#define D_ 1024
#define S_ 1024
#define B_ 2
#define H_ 16
#define F_ 4096
#define L_ 6

typedef __bf16 bf16x8 __attribute__((ext_vector_type(8)));
typedef float f32x4 __attribute__((ext_vector_type(4)));

__device__ __forceinline__ unsigned short f2bf(float f){
  union { float f; unsigned u; } v; v.f = f;
  unsigned r = v.u + 0x7fffu + ((v.u >> 16) & 1u);
  return (unsigned short)(r >> 16);
}
__device__ __forceinline__ uint pk2(float lo, float hi){
  return (uint)f2bf(lo) | ((uint)f2bf(hi) << 16);
}
__device__ __forceinline__ uint4 pack8(float4 a, float4 b){
  uint4 r; r.x = pk2(a.x,a.y); r.y = pk2(a.z,a.w); r.z = pk2(b.x,b.y); r.w = pk2(b.z,b.w); return r;
}

// ---------------- embedding ----------------
__global__ void k_embed(const int* __restrict__ ids, const float* __restrict__ tok,
                        const float* __restrict__ pos, float* __restrict__ x){
  int row = blockIdx.x;            // b*S + s
  int s = row & (S_-1);
  int id = ids[row];
  int t = threadIdx.x;
  float4 te = ((const float4*)(tok + (size_t)id*D_))[t];
  float4 pe = ((const float4*)(pos + (size_t)s*D_))[t];
  float4 o; o.x=te.x+pe.x; o.y=te.y+pe.y; o.z=te.z+pe.z; o.w=te.w+pe.w;
  ((float4*)(x + (size_t)row*D_))[t] = o;
}

// ---------------- layernorm -> bf16 ----------------
__global__ void k_ln(const float* __restrict__ x, const float* __restrict__ g,
                     const float* __restrict__ b, ushort* __restrict__ h){
  int row = blockIdx.x;
  int t = threadIdx.x;
  float4 v = ((const float4*)(x + (size_t)row*D_))[t];
  float s1 = v.x+v.y+v.z+v.w;
  float s2 = v.x*v.x+v.y*v.y+v.z*v.z+v.w*v.w;
  #pragma unroll
  for (int o=1;o<64;o<<=1){ s1 += __shfl_xor(s1,o); s2 += __shfl_xor(s2,o); }
  __shared__ float sm[8];
  int w = t>>6;
  if ((t&63)==0){ sm[w]=s1; sm[4+w]=s2; }
  __syncthreads();
  s1 = sm[0]+sm[1]+sm[2]+sm[3];
  s2 = sm[4]+sm[5]+sm[6]+sm[7];
  float mu = s1 * (1.0f/D_);
  float var = s2 * (1.0f/D_) - mu*mu;
  float rs = rsqrtf(var + 1e-5f);
  float4 gv = ((const float4*)g)[t];
  float4 bv = ((const float4*)b)[t];
  union { ushort u[4]; uint2 p; } o;
  o.u[0] = f2bf((v.x-mu)*rs*gv.x + bv.x);
  o.u[1] = f2bf((v.y-mu)*rs*gv.y + bv.y);
  o.u[2] = f2bf((v.z-mu)*rs*gv.z + bv.z);
  o.u[3] = f2bf((v.w-mu)*rs*gv.w + bv.w);
  ((uint2*)(h + (size_t)row*D_))[t] = o.p;
}

// ---------------- final layernorm (last token per batch) -> fp32 out ----------------
__global__ void k_lnf(const float* __restrict__ x, const float* __restrict__ g,
                      const float* __restrict__ b, float* __restrict__ out){
  int row = blockIdx.x*S_ + (S_-1);
  int t = threadIdx.x;
  float4 v = ((const float4*)(x + (size_t)row*D_))[t];
  float s1 = v.x+v.y+v.z+v.w;
  float s2 = v.x*v.x+v.y*v.y+v.z*v.z+v.w*v.w;
  #pragma unroll
  for (int o=1;o<64;o<<=1){ s1 += __shfl_xor(s1,o); s2 += __shfl_xor(s2,o); }
  __shared__ float sm[8];
  int w = t>>6;
  if ((t&63)==0){ sm[w]=s1; sm[4+w]=s2; }
  __syncthreads();
  s1 = sm[0]+sm[1]+sm[2]+sm[3];
  s2 = sm[4]+sm[5]+sm[6]+sm[7];
  float mu = s1 * (1.0f/D_);
  float var = s2 * (1.0f/D_) - mu*mu;
  float rs = rsqrtf(var + 1e-5f);
  float4 gv = ((const float4*)g)[t];
  float4 bv = ((const float4*)b)[t];
  float4 y;
  y.x = (v.x-mu)*rs*gv.x + bv.x;
  y.y = (v.y-mu)*rs*gv.y + bv.y;
  y.z = (v.z-mu)*rs*gv.z + bv.z;
  y.w = (v.w-mu)*rs*gv.w + bv.w;
  ((float4*)(out + (size_t)blockIdx.x*D_))[t] = y;
}

// ---------------- GEMM: C[m,n] (+)= sum_k A_bf16[m,k] * B_f32[n,k] ----------------
// BM=BN=128, BK=32, 256 threads (4 waves, 2x2), each wave 64x64 via 4x4 MFMA 16x16x32.
// blockIdx.z selects among up to 3 (B,C) pairs (fused QKV / W1W3 launches).
#define LDA 40   // ushort stride: 80B rows -> 16B aligned, ~2-way banks on b128 reads
template<int OP>  // 0: C = acc, 1: C += acc (residual)
__global__ __launch_bounds__(256) void k_gemm_bt(
    const ushort* __restrict__ A,
    const float* __restrict__ B0, const float* __restrict__ B1, const float* __restrict__ B2,
    float* __restrict__ C0, float* __restrict__ C1, float* __restrict__ C2,
    int N, int K){
  const int z = blockIdx.z;
  const float* B = (z==0) ? B0 : ((z==1) ? B1 : B2);
  float* C = (z==0) ? C0 : ((z==1) ? C1 : C2);
  const int m0 = blockIdx.x*128, n0 = blockIdx.y*128;
  __shared__ ushort As[128*LDA];
  __shared__ ushort Bs[128*LDA];
  const int t = threadIdx.x;
  const int lane = t & 63, w = t >> 6;
  const int wm = (w & 1)*64, wn = (w >> 1)*64;
  const int fr = lane & 15, fk = (lane >> 4)*8;
  const int trow = t >> 1, tcol = (t & 1)*16;
  const ushort* Ag = A + (size_t)(m0 + trow)*K + tcol;
  const float*  Bg = B + (size_t)(n0 + trow)*K + tcol;
  ushort* Asw = &As[trow*LDA + tcol];
  ushort* Bsw = &Bs[trow*LDA + tcol];

  f32x4 acc[4][4];
  #pragma unroll
  for (int i=0;i<4;i++)
    #pragma unroll
    for (int j=0;j<4;j++)
      #pragma unroll
      for (int r=0;r<4;r++) acc[i][j][r] = 0.0f;

  for (int k0 = 0; k0 < K; k0 += 32){
    uint4 a0 = *(const uint4*)(Ag + k0);
    uint4 a1 = *(const uint4*)(Ag + k0 + 8);
    float4 q0 = *(const float4*)(Bg + k0);
    float4 q1 = *(const float4*)(Bg + k0 + 4);
    float4 q2 = *(const float4*)(Bg + k0 + 8);
    float4 q3 = *(const float4*)(Bg + k0 + 12);
    __syncthreads();   // previous iter's frag reads done
    *(uint4*)(Asw)     = a0;
    *(uint4*)(Asw + 8) = a1;
    *(uint4*)(Bsw)     = pack8(q0, q1);
    *(uint4*)(Bsw + 8) = pack8(q2, q3);
    __syncthreads();
    bf16x8 af[4], bfr[4];
    #pragma unroll
    for (int i=0;i<4;i++) af[i]  = *(const bf16x8*)&As[(wm + i*16 + fr)*LDA + fk];
    #pragma unroll
    for (int j=0;j<4;j++) bfr[j] = *(const bf16x8*)&Bs[(wn + j*16 + fr)*LDA + fk];
    #pragma unroll
    for (int i=0;i<4;i++)
      #pragma unroll
      for (int j=0;j<4;j++)
        acc[i][j] = __builtin_amdgcn_mfma_f32_16x16x32_bf16(af[i], bfr[j], acc[i][j], 0, 0, 0);
  }
  // epilogue: C/D layout col=lane&15, row=(lane>>4)*4+reg
  #pragma unroll
  for (int i=0;i<4;i++){
    int row = m0 + wm + i*16 + (lane >> 4)*4;
    #pragma unroll
    for (int j=0;j<4;j++){
      int col = n0 + wn + j*16 + (lane & 15);
      float* cp = C + (size_t)row*N + col;
      #pragma unroll
      for (int r=0;r<4;r++){
        if (OP == 0) cp[(size_t)r*N] = acc[i][j][r];
        else         cp[(size_t)r*N] += acc[i][j][r];
      }
    }
  }
}

// ---------------- RoPE on Q (in place) ----------------
__global__ void k_rope_q(float* __restrict__ q){
  int idx = blockIdx.x*256 + threadIdx.x;
  int d = idx & 63;
  int s = (idx >> 10) & (S_-1);
  float v = q[idx];
  float p = __shfl_xor(v, 32);
  float rot = (d < 32) ? -p : p;
  float inv = expf(-(float)(d & 31) * 0.28782313662f);  // ln(10000)/32
  float sn, cs; sincosf((float)s * inv, &sn, &cs);
  q[idx] = v*cs + rot*sn;
}

// ---------------- RoPE on K + transpose to (bh, d, s) ----------------
__global__ void k_rope_kt(const float* __restrict__ k, float* __restrict__ kt){
  __shared__ float kl[64*68];
  int t = threadIdx.x;
  int s0 = blockIdx.x*64, bh = blockIdx.y;
  int b = bh >> 4, hh = bh & 15;
  int j = t >> 2, off = (t & 3)*16;
  const float* src = k + ((size_t)(b*S_ + s0 + j))*D_ + hh*64 + off;
  float4 r0 = ((const float4*)src)[0];
  float4 r1 = ((const float4*)src)[1];
  float4 r2 = ((const float4*)src)[2];
  float4 r3 = ((const float4*)src)[3];
  *(float4*)&kl[j*68 + off +  0] = r0;
  *(float4*)&kl[j*68 + off +  4] = r1;
  *(float4*)&kl[j*68 + off +  8] = r2;
  *(float4*)&kl[j*68 + off + 12] = r3;
  __syncthreads();
  int d = t >> 2, so = (t & 3)*16;
  float inv = expf(-(float)(d & 31) * 0.28782313662f);
  float sgn = (d < 32) ? -1.f : 1.f;
  float* dst = kt + ((size_t)bh*64 + d)*S_ + s0;
  #pragma unroll
  for (int jj = 0; jj < 16; jj++){
    int sl = so + jj;
    float v = kl[sl*68 + d];
    float p = kl[sl*68 + (d ^ 32)];
    float sn, cs; sincosf((float)(s0 + sl)*inv, &sn, &cs);
    dst[sl] = v*cs + sgn*p*sn;
  }
}

// ---------------- flash attention (causal, online softmax) -> bf16 ctx ----------------
// block: 32 queries of one (b,h); 4 waves x 8 queries; K/V chunks of 64 in LDS.
__global__ __launch_bounds__(256) void k_flash(const float* __restrict__ q,
    const float* __restrict__ kt, const float* __restrict__ v,
    ushort* __restrict__ ctx){
  __shared__ float Kl[64*64];   // [d][key]
  __shared__ float Vl[64*64];   // [key][d]
  __shared__ float Ql[64*32];   // [d][q]
  __shared__ float Pl[64*32];   // [key][q]
  int t = threadIdx.x, lane = t & 63, w = t >> 6;
  int bh = blockIdx.y, b = bh >> 4, hh = bh & 15;
  int q0 = ((int)gridDim.x - 1 - (int)blockIdx.x) * 32;  // big-q blocks first
  int qbase = q0 + w*8;
  float o[8], m[8], l[8];
  #pragma unroll
  for (int qq=0; qq<8; qq++){
    int qi = qbase + qq;
    float val = q[((size_t)(b*S_ + qi))*D_ + hh*64 + lane];
    Ql[lane*32 + w*8 + qq] = val;
    o[qq]=0.f; m[qq]=-1e30f; l[qq]=0.f;
  }
  int nch = q0/64 + 1;
  int sd = t >> 2, soff = (t & 3)*16;
  for (int c = 0; c < nch; c++){
    int k0 = c*64;
    __syncthreads();
    {
      const float* ks = kt + ((size_t)bh*64 + sd)*S_ + k0 + soff;
      float4 a0 = ((const float4*)ks)[0], a1 = ((const float4*)ks)[1],
             a2 = ((const float4*)ks)[2], a3 = ((const float4*)ks)[3];
      *(float4*)&Kl[sd*64 + soff +  0] = a0;
      *(float4*)&Kl[sd*64 + soff +  4] = a1;
      *(float4*)&Kl[sd*64 + soff +  8] = a2;
      *(float4*)&Kl[sd*64 + soff + 12] = a3;
      const float* vs = v + ((size_t)(b*S_ + k0 + sd))*D_ + hh*64 + soff;
      float4 b0 = ((const float4*)vs)[0], b1 = ((const float4*)vs)[1],
             b2 = ((const float4*)vs)[2], b3 = ((const float4*)vs)[3];
      *(float4*)&Vl[sd*64 + soff +  0] = b0;
      *(float4*)&Vl[sd*64 + soff +  4] = b1;
      *(float4*)&Vl[sd*64 + soff +  8] = b2;
      *(float4*)&Vl[sd*64 + soff + 12] = b3;
    }
    __syncthreads();
    float s[8];
    #pragma unroll
    for (int qq=0; qq<8; qq++) s[qq] = 0.f;
    for (int d=0; d<64; d++){
      float kv = Kl[d*64 + lane];
      float4 qa = *(const float4*)&Ql[d*32 + w*8];
      float4 qb = *(const float4*)&Ql[d*32 + w*8 + 4];
      s[0] += qa.x*kv; s[1] += qa.y*kv; s[2] += qa.z*kv; s[3] += qa.w*kv;
      s[4] += qb.x*kv; s[5] += qb.y*kv; s[6] += qb.z*kv; s[7] += qb.w*kv;
    }
    int key = k0 + lane;
    #pragma unroll
    for (int qq=0; qq<8; qq++){
      float sv = (key <= qbase + qq) ? s[qq]*0.125f : -1e30f;
      float mc = sv;
      #pragma unroll
      for (int ofs=1; ofs<64; ofs<<=1) mc = fmaxf(mc, __shfl_xor(mc, ofs));
      float mn = fmaxf(m[qq], mc);
      float al = expf(m[qq] - mn);
      float p  = expf(sv - mn);
      float ps = p;
      #pragma unroll
      for (int ofs=1; ofs<64; ofs<<=1) ps += __shfl_xor(ps, ofs);
      l[qq] = l[qq]*al + ps;
      m[qq] = mn;
      o[qq] *= al;
      Pl[lane*32 + w*8 + qq] = p;
    }
    for (int j=0; j<64; j++){
      float vv = Vl[j*64 + lane];
      float4 pa = *(const float4*)&Pl[j*32 + w*8];
      float4 pb = *(const float4*)&Pl[j*32 + w*8 + 4];
      o[0] += pa.x*vv; o[1] += pa.y*vv; o[2] += pa.z*vv; o[3] += pa.w*vv;
      o[4] += pb.x*vv; o[5] += pb.y*vv; o[6] += pb.z*vv; o[7] += pb.w*vv;
    }
  }
  #pragma unroll
  for (int qq=0; qq<8; qq++)
    ctx[((size_t)(b*S_ + qbase + qq))*D_ + hh*64 + lane] = f2bf(o[qq] / l[qq]);
}

// ---------------- silu(g1) * g3 -> bf16 ----------------
__global__ void k_silu(const float* __restrict__ g1, const float* __restrict__ g3,
                       ushort* __restrict__ p){
  int idx = blockIdx.x*256 + threadIdx.x;
  float4 a = ((const float4*)g1)[idx];
  float4 b = ((const float4*)g3)[idx];
  union { ushort u[4]; uint2 v; } o;
  o.u[0] = f2bf(a.x / (1.f + expf(-a.x)) * b.x);
  o.u[1] = f2bf(a.y / (1.f + expf(-a.y)) * b.y);
  o.u[2] = f2bf(a.z / (1.f + expf(-a.z)) * b.z);
  o.u[3] = f2bf(a.w / (1.f + expf(-a.w)) * b.w);
  ((uint2*)p)[idx] = o.v;
}

extern "C" void kernel_launch(void* const* d_in, const int* in_sizes, int n_in,
                              void* d_out, int out_size, void* d_ws, size_t ws_size,
                              hipStream_t stream) {
  const int*   ids  = (const int*)  d_in[0];
  const float* tok  = (const float*)d_in[1];
  const float* pos  = (const float*)d_in[2];
  const float* wq   = (const float*)d_in[3];
  const float* wk   = (const float*)d_in[4];
  const float* wv   = (const float*)d_in[5];
  const float* wo   = (const float*)d_in[6];
  const float* w1   = (const float*)d_in[7];
  const float* w2   = (const float*)d_in[8];
  const float* w3   = (const float*)d_in[9];
  const float* ln1g = (const float*)d_in[10];
  const float* ln1b = (const float*)d_in[11];
  const float* ln2g = (const float*)d_in[12];
  const float* ln2b = (const float*)d_in[13];
  const float* lnfg = (const float*)d_in[14];
  const float* lnfb = (const float*)d_in[15];

  char* wsb = (char*)d_ws;
  float*  x  = (float*) (wsb);
  ushort* h  = (ushort*)(wsb + (size_t)8*1024*1024);
  float*  qb = (float*) (wsb + (size_t)12*1024*1024);
  float*  kb = (float*) (wsb + (size_t)20*1024*1024);
  float*  kt = (float*) (wsb + (size_t)28*1024*1024);
  float*  vb = (float*) (wsb + (size_t)36*1024*1024);
  ushort* cx = (ushort*)(wsb + (size_t)44*1024*1024);
  float*  g1 = (float*) (wsb + (size_t)48*1024*1024);
  float*  g3 = (float*) (wsb + (size_t)80*1024*1024);
  ushort* pb = (ushort*)(wsb + (size_t)112*1024*1024);  // total 128 MB

  k_embed<<<B_*S_, 256, 0, stream>>>(ids, tok, pos, x);

  for (int l = 0; l < L_; l++){
    size_t od = (size_t)l*D_*D_;
    size_t fd = (size_t)l*F_*D_;
    k_ln<<<B_*S_, 256, 0, stream>>>(x, ln1g + l*D_, ln1b + l*D_, h);
    // fused Q/K/V
    k_gemm_bt<0><<<dim3(16, 8, 3), 256, 0, stream>>>(h, wq + od, wk + od, wv + od,
                                                     qb, kb, vb, D_, D_);
    k_rope_q<<<(B_*S_*D_)/256, 256, 0, stream>>>(qb);
    k_rope_kt<<<dim3(S_/64, B_*H_), 256, 0, stream>>>(kb, kt);
    k_flash<<<dim3(S_/32, B_*H_), 256, 0, stream>>>(qb, kt, vb, cx);
    // attn out projection + residual
    k_gemm_bt<1><<<dim3(16, 8, 1), 256, 0, stream>>>(cx, wo + od, nullptr, nullptr,
                                                     x, nullptr, nullptr, D_, D_);
    k_ln<<<B_*S_, 256, 0, stream>>>(x, ln2g + l*D_, ln2b + l*D_, h);
    // fused W1/W3
    k_gemm_bt<0><<<dim3(16, 32, 2), 256, 0, stream>>>(h, w1 + fd, w3 + fd, nullptr,
                                                      g1, g3, nullptr, F_, D_);
    k_silu<<<(B_*S_*F_)/1024, 256, 0, stream>>>(g1, g3, pb);
    // W2 + residual
    k_gemm_bt<1><<<dim3(16, 8, 1), 256, 0, stream>>>(pb, w2 + fd, nullptr, nullptr,
                                                     x, nullptr, nullptr, D_, F_);
  }

  k_lnf<<<B_, 256, 0, stream>>>(x, lnfg, lnfb, (float*)d_out);
}